// Round 1
// baseline (11827.480 us; speedup 1.0000x reference)
//
#include <hip/hip_runtime.h>
#include <math.h>

// Problem constants
#define TLEN    960000          // samples per batch
#define BATCH   16
#define KF      144000          // filter length (KP taps + the appended 1.0)
#define KP      143999          // ir_param length
#define ROW     1104064         // KF + TLEN + 64 prefetch pad (per-batch padded row in xbp)
#define HRP_PAD 512
#define HRPL    144768          // 512 front pad + KF + 256 back pad (per shifted copy)
#define NGROUP  1126            // 4504 chunks of 32 s-values = KF + 128 band

typedef __attribute__((ext_vector_type(8))) short bf16x8;
typedef __attribute__((ext_vector_type(4))) float f32x4;

__device__ __forceinline__ unsigned short f2bf(float f) {
  unsigned int u = __float_as_uint(f);
  u += 0x7FFFu + ((u >> 16) & 1u);   // RNE
  return (unsigned short)(u >> 16);
}

// 8 shifted copies of the reversed filter hr = [tanh(ir_param), 1.0], zero-padded.
// hrp[m][i] = hrval(i - 512 - m); copy m gives every lane a 16B-aligned fragment start.
__global__ __launch_bounds__(256) void build_hrp_kernel(const float* __restrict__ irp,
                                                        unsigned short* __restrict__ hrp) {
  int idx = blockIdx.x * 256 + threadIdx.x;
  if (idx >= 8 * HRPL) return;
  int m = idx / HRPL;
  int i = idx - m * HRPL;
  int t = i - HRP_PAD - m;
  unsigned short v = 0;
  if (t >= 0 && t <= KP) {
    v = (t == KP) ? (unsigned short)0x3F80 /*1.0 bf16*/ : f2bf(tanhf(irp[t]));
  }
  hrp[idx] = v;
}

// Zero-padded bf16 input: xbp[b][i] = bf16(x[b][i - KF]) for valid range, 0 in the
// KF-long causal front pad and the 64-elem prefetch tail pad.
__global__ __launch_bounds__(256) void build_xbp_kernel(const float* __restrict__ x,
                                                        unsigned short* __restrict__ xbp) {
  int idx = blockIdx.x * 256 + threadIdx.x;
  if (idx >= BATCH * ROW) return;
  int b = idx / ROW;
  int i = idx - b * ROW;
  float v = 0.f;
  int s = i - KF;
  if (s >= 0 && s < TLEN) v = x[b * TLEN + s];
  xbp[idx] = f2bf(v);
}

// One wave = 128 consecutive outputs t for all 16 batches (8 MFMA tiles, D[m=b][n=t]).
// K-loop streams the s-band (KF+128 values, 4504 chunks of 32).
// Per chunk: 1 A-load (x, dwordx4), 2 new Toeplitz filter fragments (dwordx4, L1-hot),
// 8 MFMAs. Filter fragments rotate in an 8-slot FIFO: frag(r, c+1) == frag(r-2, c).
__global__ __launch_bounds__(256) void conv_main_kernel(const unsigned short* __restrict__ xbp,
                                                        const unsigned short* __restrict__ hrp,
                                                        float* __restrict__ out) {
  const int tid  = threadIdx.x;
  const int wv   = tid >> 6;
  const int lane = tid & 63;
  const int l15  = lane & 15;       // A: batch row ; B/D: column
  const int quad = lane >> 4;
  const int wid  = blockIdx.x * 4 + wv;      // 0..7499
  const int Tw   = wid * 128;                // this wave's first output sample

  // x fragment pointer: A[m=l15][k=quad*8+j] = xbp[l15][Tw + 32c + quad*8 + j]
  const unsigned short* ap = xbp + l15 * ROW + Tw + quad * 8;

  // filter fragment base. Element index E(w) = 511 - l15 + 8*quad + 16*w in logical
  // hr coords (+512 pad). Copy m = E0 & 7 makes (E0 + m) a multiple of 8 -> 16B aligned.
  const int E0 = 511 - l15 + 8 * quad;
  const int m  = E0 & 7;
  const unsigned short* fp = hrp + m * HRPL + (E0 + m);

  bf16x8 F[8];
#pragma unroll
  for (int w = -7; w <= 0; ++w) F[w & 7] = *(const bf16x8*)(fp + 16 * w);

  bf16x8 a0 = *(const bf16x8*)(ap);          // chunk 0
  bf16x8 a1 = *(const bf16x8*)(ap + 32);     // chunk 1

  f32x4 acc[8] = {};

  for (int g = 0; g < NGROUP; ++g) {
    const unsigned short* fg = fp + g * 128;   // w = 8g
    const unsigned short* ag = ap + g * 128;   // chunk 4g
#pragma unroll
    for (int u = 0; u < 4; ++u) {
      bf16x8 a = (u & 1) ? a1 : a0;
      // retire the two oldest fragments first, then refill those slots (w = 2c+1, 2c+2)
      acc[7] = __builtin_amdgcn_mfma_f32_16x16x32_bf16(a, F[(2*u+1)&7], acc[7], 0,0,0);
      acc[6] = __builtin_amdgcn_mfma_f32_16x16x32_bf16(a, F[(2*u+2)&7], acc[6], 0,0,0);
      F[(2*u+1)&7] = *(const bf16x8*)(fg + 16*(2*u+1));
      F[(2*u+2)&7] = *(const bf16x8*)(fg + 16*(2*u+2));
      if (u & 1) a1 = *(const bf16x8*)(ag + 32*(u+2));   // x prefetch, distance 2 chunks
      else       a0 = *(const bf16x8*)(ag + 32*(u+2));
      acc[5] = __builtin_amdgcn_mfma_f32_16x16x32_bf16(a, F[(2*u+3)&7], acc[5], 0,0,0);
      acc[4] = __builtin_amdgcn_mfma_f32_16x16x32_bf16(a, F[(2*u+4)&7], acc[4], 0,0,0);
      acc[3] = __builtin_amdgcn_mfma_f32_16x16x32_bf16(a, F[(2*u+5)&7], acc[3], 0,0,0);
      acc[2] = __builtin_amdgcn_mfma_f32_16x16x32_bf16(a, F[(2*u+6)&7], acc[2], 0,0,0);
      acc[1] = __builtin_amdgcn_mfma_f32_16x16x32_bf16(a, F[(2*u+7)&7], acc[1], 0,0,0);
      acc[0] = __builtin_amdgcn_mfma_f32_16x16x32_bf16(a, F[(2*u+8)&7], acc[0], 0,0,0);
    }
  }

  // Epilogue: C/D layout col = lane&15 (t), row = quad*4 + reg (batch)
#pragma unroll
  for (int r = 0; r < 8; ++r) {
    int t = Tw + 16 * r + l15;
#pragma unroll
    for (int k = 0; k < 4; ++k) {
      out[(quad * 4 + k) * TLEN + t] = acc[r][k];
    }
  }
}

extern "C" void kernel_launch(void* const* d_in, const int* in_sizes, int n_in,
                              void* d_out, int out_size, void* d_ws, size_t ws_size,
                              hipStream_t stream) {
  const float* x   = (const float*)d_in[0];   // (16,1,960000) f32
  const float* irp = (const float*)d_in[1];   // (1,1,143999) f32
  float* out = (float*)d_out;                 // (16,1,960000) f32

  // workspace layout: [ hrp: 8*HRPL bf16 = 2,316,288 B | xbp: 16*ROW bf16 = 35,330,048 B ]
  unsigned short* hrp = (unsigned short*)d_ws;
  unsigned short* xbp = (unsigned short*)((char*)d_ws + (size_t)(8 * HRPL) * 2);

  build_hrp_kernel<<<(8 * HRPL + 255) / 256, 256, 0, stream>>>(irp, hrp);
  build_xbp_kernel<<<(BATCH * ROW + 255) / 256, 256, 0, stream>>>(x, xbp);
  conv_main_kernel<<<1875, 256, 0, stream>>>(xbp, hrp, out);
}

// Round 2
// 6738.128 us; speedup vs baseline: 1.7553x; 1.7553x over previous
//
#include <hip/hip_runtime.h>
#include <math.h>

// Problem constants
#define TLEN    960000          // samples per batch
#define BATCH   16
#define KF      144000          // filter length (KP taps + the appended 1.0)
#define KP      143999          // ir_param length
#define ROW     1104320         // KF + TLEN + 320 prefetch pad (per-batch padded row in xbp)
#define HRP_PAD 512
#define HRPL    145024          // 512 front pad + KF + back pad (per shifted copy)
#define NGROUP  564             // 4512 chunks of 32 s-values = KF + 384 band (tail chunks hit zero taps)

typedef __attribute__((ext_vector_type(8))) short bf16x8;
typedef __attribute__((ext_vector_type(4))) float f32x4;

__device__ __forceinline__ unsigned short f2bf(float f) {
  unsigned int u = __float_as_uint(f);
  u += 0x7FFFu + ((u >> 16) & 1u);   // RNE
  return (unsigned short)(u >> 16);
}

// 8 shifted copies of the reversed filter hr = [tanh(ir_param), 1.0], zero-padded.
// hrp[m][i] = hrval(i - 512 - m); copy m gives every lane a 16B-aligned fragment start.
// Out-of-range taps (t<0 or t>KP) are 0, so over-band fragments contribute nothing.
__global__ __launch_bounds__(256) void build_hrp_kernel(const float* __restrict__ irp,
                                                        unsigned short* __restrict__ hrp) {
  int idx = blockIdx.x * 256 + threadIdx.x;
  if (idx >= 8 * HRPL) return;
  int m = idx / HRPL;
  int i = idx - m * HRPL;
  int t = i - HRP_PAD - m;
  unsigned short v = 0;
  if (t >= 0 && t <= KP) {
    v = (t == KP) ? (unsigned short)0x3F80 /*1.0 bf16*/ : f2bf(tanhf(irp[t]));
  }
  hrp[idx] = v;
}

// Zero-padded bf16 input: xbp[b][i] = bf16(x[b][i - KF]) for valid range, 0 in the
// KF-long causal front pad and the prefetch tail pad.
__global__ __launch_bounds__(256) void build_xbp_kernel(const float* __restrict__ x,
                                                        unsigned short* __restrict__ xbp) {
  int idx = blockIdx.x * 256 + threadIdx.x;
  if (idx >= BATCH * ROW) return;
  int b = idx / ROW;
  int i = idx - b * ROW;
  float v = 0.f;
  int s = i - KF;
  if (s >= 0 && s < TLEN) v = x[b * TLEN + s];
  xbp[idx] = f2bf(v);
}

// One wave = 256 consecutive outputs t for all 16 batches (16 MFMA tiles, D[m=b][n=t]).
// Per 32-K chunk: 16 MFMAs share ONE A-fragment (x), 2 new Toeplitz filter fragments
// enter a 16-slot FIFO (frag(r,c+1)==frag(r-2,c)), A prefetched 4 chunks ahead via a
// 4-slot ring. 16 MFMAs (~78 cyc) per 3 loads -> latency-tolerant, L1 demand 38 B/cyc.
__global__ __launch_bounds__(192) void conv_main_kernel(const unsigned short* __restrict__ xbp,
                                                        const unsigned short* __restrict__ hrp,
                                                        float* __restrict__ out) {
  const int tid  = threadIdx.x;
  const int wv   = tid >> 6;
  const int lane = tid & 63;
  const int l15  = lane & 15;       // A: batch row ; B/D: column
  const int quad = lane >> 4;
  const int wid  = blockIdx.x * 3 + wv;      // 0..3749
  const int Tw   = wid * 256;                // this wave's first output sample

  // x fragment pointer: A[m=l15][k=quad*8+j] = xbp[l15][Tw + 32c + quad*8 + j]
  const unsigned short* ap = xbp + l15 * ROW + Tw + quad * 8;

  // filter fragment base. Element index E(w) = 511 - l15 + 8*quad + 16*w in padded
  // hr coords. Copy m = E0 & 7 makes (E0 + m) a multiple of 8 -> 16B aligned.
  const int E0 = 511 - l15 + 8 * quad;
  const int m  = E0 & 7;
  const unsigned short* fp = hrp + m * HRPL + (E0 + m);

  bf16x8 F[16];
#pragma unroll
  for (int w = -15; w <= 0; ++w) F[w & 15] = *(const bf16x8*)(fp + 16 * w);

  bf16x8 aR[4];
#pragma unroll
  for (int i = 0; i < 4; ++i) aR[i] = *(const bf16x8*)(ap + 32 * i);

  f32x4 acc[16] = {};

  for (int g = 0; g < NGROUP; ++g) {
    const unsigned short* fg = fp + g * 256;   // fragment offsets, 16 per chunk-pair
    const unsigned short* ag = ap + g * 256;   // x chunks, 8 per group
#pragma unroll
    for (int u = 0; u < 8; ++u) {
      bf16x8 a = aR[u & 3];
      // retire the two oldest fragments first, then refill those slots
      acc[15] = __builtin_amdgcn_mfma_f32_16x16x32_bf16(a, F[(2*u+ 1)&15], acc[15], 0,0,0);
      acc[14] = __builtin_amdgcn_mfma_f32_16x16x32_bf16(a, F[(2*u+ 2)&15], acc[14], 0,0,0);
      F[(2*u+1)&15] = *(const bf16x8*)(fg + 32*u + 16);
      F[(2*u+2)&15] = *(const bf16x8*)(fg + 32*u + 32);
      aR[u & 3]     = *(const bf16x8*)(ag + 32*u + 128);   // x prefetch, distance 4 chunks
      acc[13] = __builtin_amdgcn_mfma_f32_16x16x32_bf16(a, F[(2*u+ 3)&15], acc[13], 0,0,0);
      acc[12] = __builtin_amdgcn_mfma_f32_16x16x32_bf16(a, F[(2*u+ 4)&15], acc[12], 0,0,0);
      acc[11] = __builtin_amdgcn_mfma_f32_16x16x32_bf16(a, F[(2*u+ 5)&15], acc[11], 0,0,0);
      acc[10] = __builtin_amdgcn_mfma_f32_16x16x32_bf16(a, F[(2*u+ 6)&15], acc[10], 0,0,0);
      acc[ 9] = __builtin_amdgcn_mfma_f32_16x16x32_bf16(a, F[(2*u+ 7)&15], acc[ 9], 0,0,0);
      acc[ 8] = __builtin_amdgcn_mfma_f32_16x16x32_bf16(a, F[(2*u+ 8)&15], acc[ 8], 0,0,0);
      acc[ 7] = __builtin_amdgcn_mfma_f32_16x16x32_bf16(a, F[(2*u+ 9)&15], acc[ 7], 0,0,0);
      acc[ 6] = __builtin_amdgcn_mfma_f32_16x16x32_bf16(a, F[(2*u+10)&15], acc[ 6], 0,0,0);
      acc[ 5] = __builtin_amdgcn_mfma_f32_16x16x32_bf16(a, F[(2*u+11)&15], acc[ 5], 0,0,0);
      acc[ 4] = __builtin_amdgcn_mfma_f32_16x16x32_bf16(a, F[(2*u+12)&15], acc[ 4], 0,0,0);
      acc[ 3] = __builtin_amdgcn_mfma_f32_16x16x32_bf16(a, F[(2*u+13)&15], acc[ 3], 0,0,0);
      acc[ 2] = __builtin_amdgcn_mfma_f32_16x16x32_bf16(a, F[(2*u+14)&15], acc[ 2], 0,0,0);
      acc[ 1] = __builtin_amdgcn_mfma_f32_16x16x32_bf16(a, F[(2*u+15)&15], acc[ 1], 0,0,0);
      acc[ 0] = __builtin_amdgcn_mfma_f32_16x16x32_bf16(a, F[(2*u+16)&15], acc[ 0], 0,0,0);
    }
  }

  // Epilogue: C/D layout col = lane&15 (t), row = quad*4 + reg (batch)
#pragma unroll
  for (int r = 0; r < 16; ++r) {
    int t = Tw + 16 * r + l15;
#pragma unroll
    for (int k = 0; k < 4; ++k) {
      out[(quad * 4 + k) * TLEN + t] = acc[r][k];
    }
  }
}

extern "C" void kernel_launch(void* const* d_in, const int* in_sizes, int n_in,
                              void* d_out, int out_size, void* d_ws, size_t ws_size,
                              hipStream_t stream) {
  const float* x   = (const float*)d_in[0];   // (16,1,960000) f32
  const float* irp = (const float*)d_in[1];   // (1,1,143999) f32
  float* out = (float*)d_out;                 // (16,1,960000) f32

  // workspace layout: [ hrp: 8*HRPL bf16 = 2,320,384 B | xbp: 16*ROW bf16 = 35,338,240 B ]
  unsigned short* hrp = (unsigned short*)d_ws;
  unsigned short* xbp = (unsigned short*)((char*)d_ws + (size_t)(8 * HRPL) * 2);

  build_hrp_kernel<<<(8 * HRPL + 255) / 256, 256, 0, stream>>>(irp, hrp);
  build_xbp_kernel<<<(BATCH * ROW + 255) / 256, 256, 0, stream>>>(x, xbp);
  // 3750 waves (960000/256), 3 waves per 192-thread block -> 1250 blocks, no guards
  conv_main_kernel<<<1250, 192, 0, stream>>>(xbp, hrp, out);
}

// Round 3
// 5661.085 us; speedup vs baseline: 2.0893x; 1.1903x over previous
//
#include <hip/hip_runtime.h>
#include <math.h>

// Problem constants
#define TLEN    960000          // samples per batch
#define BATCH   16
#define KF      144000          // filter length (KP taps + the appended 1.0)
#define KP      143999          // ir_param length
#define ROW     1104320         // KF + TLEN + 320 prefetch pad (per-batch padded row in xbp)
#define HRP_PAD 512
#define HRPL    145536          // 512 front pad + KF + back pad (covers max frag idx 145,189)
#define NGQ     141             // groups per K-quarter: 4512 chunks = 4 quarters * 1128 (141*8)
#define QCH     1128            // chunks per quarter

typedef __attribute__((ext_vector_type(8))) short bf16x8;
typedef __attribute__((ext_vector_type(4))) float f32x4;

__device__ __forceinline__ unsigned short f2bf(float f) {
  unsigned int u = __float_as_uint(f);
  u += 0x7FFFu + ((u >> 16) & 1u);   // RNE
  return (unsigned short)(u >> 16);
}

// 8 shifted copies of the reversed filter hr = [tanh(ir_param), 1.0], zero-padded.
// hrp[m][i] = hrval(i - 512 - m); copy m gives every lane a 16B-aligned fragment start.
// Out-of-range taps (t<0 or t>KP) are 0, so over-band fragments contribute nothing.
__global__ __launch_bounds__(256) void build_hrp_kernel(const float* __restrict__ irp,
                                                        unsigned short* __restrict__ hrp) {
  int idx = blockIdx.x * 256 + threadIdx.x;
  if (idx >= 8 * HRPL) return;
  int m = idx / HRPL;
  int i = idx - m * HRPL;
  int t = i - HRP_PAD - m;
  unsigned short v = 0;
  if (t >= 0 && t <= KP) {
    v = (t == KP) ? (unsigned short)0x3F80 /*1.0 bf16*/ : f2bf(tanhf(irp[t]));
  }
  hrp[idx] = v;
}

// Zero-padded bf16 input: xbp[b][i] = bf16(x[b][i - KF]) for valid range, 0 in the
// KF-long causal front pad and the prefetch tail pad.
__global__ __launch_bounds__(256) void build_xbp_kernel(const float* __restrict__ x,
                                                        unsigned short* __restrict__ xbp) {
  int idx = blockIdx.x * 256 + threadIdx.x;
  if (idx >= BATCH * ROW) return;
  int b = idx / ROW;
  int i = idx - b * ROW;
  float v = 0.f;
  int s = i - KF;
  if (s >= 0 && s < TLEN) v = x[b * TLEN + s];
  xbp[idx] = f2bf(v);
}

// Block = one 256-output tile (all 16 batches); its 4 waves each cover one K-quarter
// (1128 chunks of 32). Per chunk: 16 MFMAs share one A-fragment; 2 new Toeplitz filter
// fragments enter a 16-slot FIFO (frag(r,c+1)==frag(r-2,c)); A prefetched 4 chunks
// ahead. Partials reduced in LDS (deterministic), wave 3 stores. K-split x4 makes jobs
// short: 3750 blocks / (3 blocks/CU * 256 CU) = 4.88 rounds -> 97.7% slot packing vs
// 61% for full-K waves.
__global__ __launch_bounds__(256) void conv_main_kernel(const unsigned short* __restrict__ xbp,
                                                        const unsigned short* __restrict__ hrp,
                                                        float* __restrict__ out) {
  const int tid  = threadIdx.x;
  const int wv   = tid >> 6;        // K-quarter index 0..3
  const int lane = tid & 63;
  const int l15  = lane & 15;       // A: batch row ; B/D: column
  const int quad = lane >> 4;
  const int Tw   = blockIdx.x * 256;   // this block's first output sample
  const int cq   = wv * QCH;           // first chunk of this wave's K-quarter

  // x fragment pointer: A[m=l15][k] = xbp[l15][Tw + 32*(cq+c) + quad*8 + j]
  const unsigned short* ap = xbp + l15 * ROW + Tw + cq * 32 + quad * 8;

  // filter fragment base. Fragment w, lane (l15,quad), elem j has value
  // hrval(8*quad - l15 - 1 + 16w + j). Copy m = E0&7 -> 16B-aligned loads.
  const int E0 = 511 - l15 + 8 * quad;
  const int m  = E0 & 7;
  const unsigned short* fp = hrp + m * HRPL + (E0 + m) + cq * 32;  // +16*(2*cq)

  bf16x8 F[16];
#pragma unroll
  for (int w = -15; w <= 0; ++w) F[w & 15] = *(const bf16x8*)(fp + 16 * w);

  bf16x8 aR[4];
#pragma unroll
  for (int i = 0; i < 4; ++i) aR[i] = *(const bf16x8*)(ap + 32 * i);

  f32x4 acc[16] = {};

  for (int g = 0; g < NGQ; ++g) {
    const unsigned short* fg = fp + g * 256;   // fragment offsets, 16 per 8-chunk group
    const unsigned short* ag = ap + g * 256;   // x chunks, 8 per group
#pragma unroll
    for (int u = 0; u < 8; ++u) {
      bf16x8 a = aR[u & 3];
      // retire the two oldest fragments first, then refill those slots
      acc[15] = __builtin_amdgcn_mfma_f32_16x16x32_bf16(a, F[(2*u+ 1)&15], acc[15], 0,0,0);
      acc[14] = __builtin_amdgcn_mfma_f32_16x16x32_bf16(a, F[(2*u+ 2)&15], acc[14], 0,0,0);
      F[(2*u+1)&15] = *(const bf16x8*)(fg + 32*u + 16);
      F[(2*u+2)&15] = *(const bf16x8*)(fg + 32*u + 32);
      aR[u & 3]     = *(const bf16x8*)(ag + 32*u + 128);   // x prefetch, distance 4 chunks
      acc[13] = __builtin_amdgcn_mfma_f32_16x16x32_bf16(a, F[(2*u+ 3)&15], acc[13], 0,0,0);
      acc[12] = __builtin_amdgcn_mfma_f32_16x16x32_bf16(a, F[(2*u+ 4)&15], acc[12], 0,0,0);
      acc[11] = __builtin_amdgcn_mfma_f32_16x16x32_bf16(a, F[(2*u+ 5)&15], acc[11], 0,0,0);
      acc[10] = __builtin_amdgcn_mfma_f32_16x16x32_bf16(a, F[(2*u+ 6)&15], acc[10], 0,0,0);
      acc[ 9] = __builtin_amdgcn_mfma_f32_16x16x32_bf16(a, F[(2*u+ 7)&15], acc[ 9], 0,0,0);
      acc[ 8] = __builtin_amdgcn_mfma_f32_16x16x32_bf16(a, F[(2*u+ 8)&15], acc[ 8], 0,0,0);
      acc[ 7] = __builtin_amdgcn_mfma_f32_16x16x32_bf16(a, F[(2*u+ 9)&15], acc[ 7], 0,0,0);
      acc[ 6] = __builtin_amdgcn_mfma_f32_16x16x32_bf16(a, F[(2*u+10)&15], acc[ 6], 0,0,0);
      acc[ 5] = __builtin_amdgcn_mfma_f32_16x16x32_bf16(a, F[(2*u+11)&15], acc[ 5], 0,0,0);
      acc[ 4] = __builtin_amdgcn_mfma_f32_16x16x32_bf16(a, F[(2*u+12)&15], acc[ 4], 0,0,0);
      acc[ 3] = __builtin_amdgcn_mfma_f32_16x16x32_bf16(a, F[(2*u+13)&15], acc[ 3], 0,0,0);
      acc[ 2] = __builtin_amdgcn_mfma_f32_16x16x32_bf16(a, F[(2*u+14)&15], acc[ 2], 0,0,0);
      acc[ 1] = __builtin_amdgcn_mfma_f32_16x16x32_bf16(a, F[(2*u+15)&15], acc[ 1], 0,0,0);
      acc[ 0] = __builtin_amdgcn_mfma_f32_16x16x32_bf16(a, F[(2*u+16)&15], acc[ 0], 0,0,0);
    }
  }

  // Deterministic cross-quarter reduce in LDS. Layout: red[(r*4+k)*64 + lane]
  // (lane stride 4B -> 2-way bank aliasing, free). Wave 0 writes, 1..2 add,
  // wave 3 adds its partial and stores.
  __shared__ float red[4096];
#pragma unroll
  for (int s = 0; s < 3; ++s) {
    if (wv == s) {
#pragma unroll
      for (int r = 0; r < 16; ++r) {
#pragma unroll
        for (int k = 0; k < 4; ++k) {
          int idx = (r * 4 + k) * 64 + lane;
          if (s == 0) red[idx] = acc[r][k];
          else        red[idx] += acc[r][k];
        }
      }
    }
    __syncthreads();
  }
  if (wv == 3) {
    // C/D layout: col = lane&15 (t), row = quad*4 + reg (batch)
#pragma unroll
    for (int r = 0; r < 16; ++r) {
      int t = Tw + 16 * r + l15;
#pragma unroll
      for (int k = 0; k < 4; ++k) {
        out[(quad * 4 + k) * TLEN + t] = red[(r * 4 + k) * 64 + lane] + acc[r][k];
      }
    }
  }
}

extern "C" void kernel_launch(void* const* d_in, const int* in_sizes, int n_in,
                              void* d_out, int out_size, void* d_ws, size_t ws_size,
                              hipStream_t stream) {
  const float* x   = (const float*)d_in[0];   // (16,1,960000) f32
  const float* irp = (const float*)d_in[1];   // (1,1,143999) f32
  float* out = (float*)d_out;                 // (16,1,960000) f32

  // workspace: [ hrp: 8*HRPL bf16 = 2,328,576 B | xbp: 16*ROW bf16 = 35,338,240 B ]
  unsigned short* hrp = (unsigned short*)d_ws;
  unsigned short* xbp = (unsigned short*)((char*)d_ws + (size_t)(8 * HRPL) * 2);

  build_hrp_kernel<<<(8 * HRPL + 255) / 256, 256, 0, stream>>>(irp, hrp);
  build_xbp_kernel<<<(BATCH * ROW + 255) / 256, 256, 0, stream>>>(x, xbp);
  // 3750 tiles of 256 outputs; block = 4 waves = 4 K-quarters of one tile
  conv_main_kernel<<<3750, 256, 0, stream>>>(xbp, hrp, out);
}